// Round 6
// baseline (112.923 us; speedup 1.0000x reference)
//
#include <hip/hip_runtime.h>

// EquivariantLinear = per-head circular correlation on Z_8^3 via 8x8x8 FFT:
//   out = IDFT( DFT(x) * V ),  V[h][f] = conj(DFT(W_h))[f] / 512.
// Round-6: kill the latency-bound 7-phase LDS structure (R5: ~34us, all pipes
// <30% busy). LDS is used ONLY for the two corner-turns (coalesced stage-in /
// write-out, 2 barriers). The whole FFT*V*IFFT runs in registers per wave:
// lane holds a p3-pencil (8 complex) per cube; in-register dft8 along held
// dim; dimension changes are 8x8 bit-swap transposes via __shfl_xor
// (masks 1,2,4 = held<->p2-lanes; 8,16,32 = held<->p1-lanes).
// Complex-pack retained: cube q = channels (c0+q, c0+q+8), same head => same V.

#define S2C 0.70710678118654752f
#define S2  18     // p2 stride (floats): 8 complex + 1 complex pad
#define S1  146    // p1 stride: 8*18 + 2
#define CST 1172   // cube stride: 8*146 + 4  (37.5 KB total -> 4 blocks/CU)

// ---------------------------------------------------------------- DFT-8 in-place
template <bool INV>
__device__ __forceinline__ void dft8(float* R, float* I)
{
    float t0r = R[0] + R[4], t0i = I[0] + I[4];
    float t1r = R[1] + R[5], t1i = I[1] + I[5];
    float t2r = R[2] + R[6], t2i = I[2] + I[6];
    float t3r = R[3] + R[7], t3i = I[3] + I[7];
    float b0r = R[0] - R[4], b0i = I[0] - I[4];
    float d1r = R[1] - R[5], d1i = I[1] - I[5];
    float d2r = R[2] - R[6], d2i = I[2] - I[6];
    float d3r = R[3] - R[7], d3i = I[3] - I[7];
    float b1r, b1i, b2r, b2i, b3r, b3i;
    if (!INV) {
        b1r = (d1r + d1i) * S2C;  b1i = (d1i - d1r) * S2C;
        b2r = d2i;                b2i = -d2r;
        b3r = (d3i - d3r) * S2C;  b3i = -(d3r + d3i) * S2C;
    } else {
        b1r = (d1r - d1i) * S2C;  b1i = (d1i + d1r) * S2C;
        b2r = -d2i;               b2i = d2r;
        b3r = -(d3r + d3i) * S2C; b3i = (d3r - d3i) * S2C;
    }
    float u0r = t0r + t2r, u0i = t0i + t2i;
    float u1r = t1r + t3r, u1i = t1i + t3i;
    float u2r = t0r - t2r, u2i = t0i - t2i;
    float e3r = t1r - t3r, e3i = t1i - t3i;
    float u3r, u3i;
    if (!INV) { u3r = e3i;  u3i = -e3r; }
    else      { u3r = -e3i; u3i = e3r;  }
    R[0] = u0r + u1r; I[0] = u0i + u1i;
    R[4] = u0r - u1r; I[4] = u0i - u1i;
    R[2] = u2r + u3r; I[2] = u2i + u3i;
    R[6] = u2r - u3r; I[6] = u2i - u3i;
    float v0r = b0r + b2r, v0i = b0i + b2i;
    float v1r = b1r + b3r, v1i = b1i + b3i;
    float v2r = b0r - b2r, v2i = b0i - b2i;
    float w3r = b1r - b3r, w3i = b1i - b3i;
    float v3r, v3i;
    if (!INV) { v3r = w3i;  v3i = -w3r; }
    else      { v3r = -w3i; v3i = w3r;  }
    R[1] = v0r + v1r; I[1] = v0i + v1i;
    R[5] = v0r - v1r; I[5] = v0i - v1i;
    R[3] = v2r + v3r; I[3] = v2i + v3i;
    R[7] = v2r - v3r; I[7] = v2i - v3i;
}

// ---------------- bit-swap transpose stage: held bit HB <-> lane bit LM ------
// After the 3 stages {1,2,4} (or {8,16,32}), held index and lane bits 0-2
// (or 3-5) are fully exchanged. Element (j_k=0, l_k=1) <-> (j_k=1, l_k=0).
template <int HB, int LM>
__device__ __forceinline__ void xstage(float* zr, float* zi, int lane)
{
    const bool sel = (lane & LM) != 0;
    #pragma unroll
    for (int j0 = 0; j0 < 8; ++j0) {
        if (j0 & HB) continue;
        const int j1 = j0 | HB;
        float sr = sel ? zr[j0] : zr[j1];
        float si = sel ? zi[j0] : zi[j1];
        sr = __shfl_xor(sr, LM, 64);
        si = __shfl_xor(si, LM, 64);
        zr[j0] = sel ? sr : zr[j0];
        zi[j0] = sel ? si : zi[j0];
        zr[j1] = sel ? zr[j1] : sr;
        zi[j1] = sel ? zi[j1] : si;
    }
}

// ---------------------------------------------------------------- prep kernel
__device__ const float CTAB8[8] = {1.f, S2C, 0.f, -S2C, -1.f, -S2C, 0.f, S2C};
__device__ const float STAB8[8] = {0.f, S2C, 1.f, S2C, 0.f, -S2C, -1.f, -S2C};

__global__ __launch_bounds__(256)
void eqfft_prep(const float* __restrict__ basis,
                const float* __restrict__ kparam,
                float2* __restrict__ V)
{
    __shared__ float Wl[512];
    __shared__ float CT[8], ST[8];
    const int tid = threadIdx.x;
    const int blk = blockIdx.x;    // 128 blocks: h = blk>>4, f-base = (blk&15)*32
    const int h   = blk >> 4;
    if (tid < 8) { CT[tid] = CTAB8[tid]; ST[tid] = STAB8[tid]; }
    #pragma unroll
    for (int t = 0; t < 2; ++t) {
        const int g = tid * 2 + t;
        const float* bp = basis + g * 24;
        float acc = 0.f;
        #pragma unroll
        for (int s = 0; s < 24; ++s) acc += bp[s] * kparam[s * 8 + h];
        Wl[(g & 63) * 8 + (g >> 6)] = acc;
    }
    __syncthreads();
    const int f  = (blk & 15) * 32 + (tid >> 3);
    const int g1 = tid & 7;
    const int f1 = f >> 6, f2 = (f >> 3) & 7, f3 = f & 7;
    const int kb = (f1 * g1) & 7;
    float pr = 0.f, pi = 0.f;
    for (int g2 = 0; g2 < 8; ++g2) {
        const int k2 = kb + f2 * g2;
        const float* wrow = &Wl[g2 * 64 + g1];
        #pragma unroll
        for (int g3 = 0; g3 < 8; ++g3) {
            const int k = (k2 + f3 * g3) & 7;
            const float w = wrow[g3 * 8];
            pr += w * CT[k];
            pi += w * ST[k];
        }
    }
    pr += __shfl_xor(pr, 1); pi += __shfl_xor(pi, 1);
    pr += __shfl_xor(pr, 2); pi += __shfl_xor(pi, 2);
    pr += __shfl_xor(pr, 4); pi += __shfl_xor(pi, 4);
    if (g1 == 0)
        V[h * 512 + f] = make_float2(pr * (1.f / 512.f), pi * (1.f / 512.f));
}

// ---------------------------------------------------------------- main kernel
// 1024 WGs x 256 thr. WG = (b = bid>>5, c0 = (bid&31)*16) = 8 packed cubes.
// Wave w owns cubes 2w, 2w+1 (head == q). Lane = (p1 = lane>>3, p2 = lane&7),
// holds the p3-pencil of its cube in registers.
__global__ __launch_bounds__(256, 4)
void eqfft_main(const float* __restrict__ x,
                const float2* __restrict__ V,
                float* __restrict__ out)
{
    __shared__ __align__(16) float lds[8 * CST];   // 37.5 KB

    const int tid = threadIdx.x;
    const int bid = blockIdx.x;
    const int b   = bid >> 5;
    const int c0  = (bid & 31) * 16;

    const float* xb = x   + (size_t)b * 262144 + c0;
    float*       ob = out + (size_t)b * 262144 + c0;

    // stage-in + pack: 64B-contiguous rows per WG (exact fetch granularity)
    #pragma unroll
    for (int t = 0; t < 4; ++t) {
        const int G = t * 256 + tid;
        const int p = G >> 1;
        const int u = G & 1;
        const float4 A  = *(const float4*)(xb + p * 512 + u * 4);
        const float4 Bv = *(const float4*)(xb + p * 512 + u * 4 + 8);
        const int base = (p >> 6) * S1 + ((p >> 3) & 7) * S2 + (p & 7) * 2;
        float* dst = lds + (u * 4) * CST + base;
        *(float2*)(dst + 0 * CST) = make_float2(A.x, Bv.x);
        *(float2*)(dst + 1 * CST) = make_float2(A.y, Bv.y);
        *(float2*)(dst + 2 * CST) = make_float2(A.z, Bv.z);
        *(float2*)(dst + 3 * CST) = make_float2(A.w, Bv.w);
    }
    __syncthreads();

    const int lane = tid & 63;
    const int wid  = tid >> 6;

    // ---- whole FFT * V * IFFT in registers; pencil LDS r/w is exclusive ----
    #pragma unroll
    for (int cc = 0; cc < 2; ++cc) {
        const int q = wid * 2 + cc;
        float zr[8], zi[8];
        float* pp = lds + q * CST + (lane >> 3) * S1 + (lane & 7) * S2;
        #pragma unroll
        for (int j = 0; j < 8; ++j) {
            const float2 z = *(const float2*)(pp + 2 * j);
            zr[j] = z.x; zi[j] = z.y;
        }
        dft8<false>(zr, zi);                                   // F along p3
        xstage<1, 1>(zr, zi, lane);                            // held <-> p2
        xstage<2, 2>(zr, zi, lane);
        xstage<4, 4>(zr, zi, lane);
        dft8<false>(zr, zi);                                   // F along p2
        xstage<1, 8>(zr, zi, lane);                            // held <-> p1
        xstage<2, 16>(zr, zi, lane);
        xstage<4, 32>(zr, zi, lane);
        dft8<false>(zr, zi);                                   // F along p1
        // layout now: held j = f1, lane = f2*8 + f3  ->  V + q*512 + lane + 64j
        const float2* vp = V + q * 512 + lane;
        #pragma unroll
        for (int j = 0; j < 8; ++j) {
            const float2 v = vp[j * 64];
            const float nr = zr[j] * v.x - zi[j] * v.y;
            zi[j] = zr[j] * v.y + zi[j] * v.x;
            zr[j] = nr;
        }
        dft8<true>(zr, zi);                                    // Fi along f1
        xstage<1, 8>(zr, zi, lane);                            // held <-> f2
        xstage<2, 16>(zr, zi, lane);
        xstage<4, 32>(zr, zi, lane);
        dft8<true>(zr, zi);                                    // Fi along f2
        xstage<1, 1>(zr, zi, lane);                            // held <-> f3
        xstage<2, 2>(zr, zi, lane);
        xstage<4, 4>(zr, zi, lane);
        dft8<true>(zr, zi);                                    // Fi along f3
        #pragma unroll
        for (int j = 0; j < 8; ++j)
            *(float2*)(pp + 2 * j) = make_float2(zr[j], zi[j]);
    }
    __syncthreads();

    // copy-out (unpack: re -> channel c, im -> channel c+8)
    #pragma unroll
    for (int t = 0; t < 4; ++t) {
        const int G = t * 256 + tid;
        const int p = G >> 1;
        const int u = G & 1;
        const int base = (p >> 6) * S1 + ((p >> 3) & 7) * S2 + (p & 7) * 2;
        const float* src = lds + (u * 4) * CST + base;
        const float2 z0 = *(const float2*)(src + 0 * CST);
        const float2 z1 = *(const float2*)(src + 1 * CST);
        const float2 z2 = *(const float2*)(src + 2 * CST);
        const float2 z3 = *(const float2*)(src + 3 * CST);
        *(float4*)(ob + p * 512 + u * 4)     = make_float4(z0.x, z1.x, z2.x, z3.x);
        *(float4*)(ob + p * 512 + u * 4 + 8) = make_float4(z0.y, z1.y, z2.y, z3.y);
    }
}

extern "C" void kernel_launch(void* const* d_in, const int* in_sizes, int n_in,
                              void* d_out, int out_size, void* d_ws, size_t ws_size,
                              hipStream_t stream)
{
    const float* x      = (const float*)d_in[0];   // [32][512][512]
    const float* basis  = (const float*)d_in[1];   // [512][24]
    const float* kparam = (const float*)d_in[2];   // [24][8]
    float* out          = (float*)d_out;
    float2* V           = (float2*)d_ws;           // 8*512*8B = 32 KB scratch

    hipLaunchKernelGGL(eqfft_prep, dim3(128),  dim3(256), 0, stream, basis, kparam, V);
    hipLaunchKernelGGL(eqfft_main, dim3(1024), dim3(256), 0, stream, x, V, out);
}

// Round 8
// 106.528 us; speedup vs baseline: 1.0600x; 1.0600x over previous
//
#include <hip/hip_runtime.h>

// EquivariantLinear = per-head circular correlation on Z_8^3 via 8x8x8 FFT:
//   out = IDFT( DFT(x) * V ),  V[h][f] = conj(DFT(W_h))[f] / 512.
// Round-7 resubmission (round 7 hit GPUAcquisitionTimeout; no data).
// R6 lesson — __shfl_xor IS the LDS pipe (ds_bpermute); register transposes
// were a net DS increase. Revert to R5's LDS dataflow with two structural
// fixes for its latency-bound 7-barrier lockstep:
//  (1) wave-autonomous phases: each wave owns cubes 2w,2w+1; DS ops from one
//      wave execute in order, so inter-phase sync is a compiler fence
//      (s_waitcnt lgkmcnt(0) + sched_barrier), not __syncthreads. Only the
//      two coalescing corner-turns keep real block barriers.
//  (2) XOR bank swizzle slot = p1*64+p2*8+(p3^p2^p1) instead of padding:
//      p1/p3 phases + corner-turns = b64 minimum (4 lanes/bank-pair),
//      p2 phases 2-way (free, m136). LDS = 32.0 KB exact -> 5 blocks/CU,
//      all 1024 blocks co-resident (no tail).
// Complex-pack retained: cube q = channels (c0+q, c0+q+8), head = q.

#define S2C 0.70710678118654752f

__device__ __forceinline__ void wave_fence()
{
    asm volatile("s_waitcnt lgkmcnt(0)" ::: "memory");
    __builtin_amdgcn_sched_barrier(0);
}

// ---------------------------------------------------------------- DFT-8 in-place
template <bool INV>
__device__ __forceinline__ void dft8(float* R, float* I)
{
    float t0r = R[0] + R[4], t0i = I[0] + I[4];
    float t1r = R[1] + R[5], t1i = I[1] + I[5];
    float t2r = R[2] + R[6], t2i = I[2] + I[6];
    float t3r = R[3] + R[7], t3i = I[3] + I[7];
    float b0r = R[0] - R[4], b0i = I[0] - I[4];
    float d1r = R[1] - R[5], d1i = I[1] - I[5];
    float d2r = R[2] - R[6], d2i = I[2] - I[6];
    float d3r = R[3] - R[7], d3i = I[3] - I[7];
    float b1r, b1i, b2r, b2i, b3r, b3i;
    if (!INV) {
        b1r = (d1r + d1i) * S2C;  b1i = (d1i - d1r) * S2C;
        b2r = d2i;                b2i = -d2r;
        b3r = (d3i - d3r) * S2C;  b3i = -(d3r + d3i) * S2C;
    } else {
        b1r = (d1r - d1i) * S2C;  b1i = (d1i + d1r) * S2C;
        b2r = -d2i;               b2i = d2r;
        b3r = -(d3r + d3i) * S2C; b3i = (d3r - d3i) * S2C;
    }
    float u0r = t0r + t2r, u0i = t0i + t2i;
    float u1r = t1r + t3r, u1i = t1i + t3i;
    float u2r = t0r - t2r, u2i = t0i - t2i;
    float e3r = t1r - t3r, e3i = t1i - t3i;
    float u3r, u3i;
    if (!INV) { u3r = e3i;  u3i = -e3r; }
    else      { u3r = -e3i; u3i = e3r;  }
    R[0] = u0r + u1r; I[0] = u0i + u1i;
    R[4] = u0r - u1r; I[4] = u0i - u1i;
    R[2] = u2r + u3r; I[2] = u2i + u3i;
    R[6] = u2r - u3r; I[6] = u2i - u3i;
    float v0r = b0r + b2r, v0i = b0i + b2i;
    float v1r = b1r + b3r, v1i = b1i + b3i;
    float v2r = b0r - b2r, v2i = b0i - b2i;
    float w3r = b1r - b3r, w3i = b1i - b3i;
    float v3r, v3i;
    if (!INV) { v3r = w3i;  v3i = -w3r; }
    else      { v3r = -w3i; v3i = w3r;  }
    R[1] = v0r + v1r; I[1] = v0i + v1i;
    R[5] = v0r - v1r; I[5] = v0i - v1i;
    R[3] = v2r + v3r; I[3] = v2i + v3i;
    R[7] = v2r - v3r; I[7] = v2i - v3i;
}

// ---------------------------------------------------------------- prep kernel
__device__ const float CTAB8[8] = {1.f, S2C, 0.f, -S2C, -1.f, -S2C, 0.f, S2C};
__device__ const float STAB8[8] = {0.f, S2C, 1.f, S2C, 0.f, -S2C, -1.f, -S2C};

__global__ __launch_bounds__(256)
void eqfft_prep(const float* __restrict__ basis,
                const float* __restrict__ kparam,
                float2* __restrict__ V)
{
    __shared__ float Wl[512];
    __shared__ float CT[8], ST[8];
    const int tid = threadIdx.x;
    const int blk = blockIdx.x;    // 128 blocks: h = blk>>4, f-base = (blk&15)*32
    const int h   = blk >> 4;
    if (tid < 8) { CT[tid] = CTAB8[tid]; ST[tid] = STAB8[tid]; }
    #pragma unroll
    for (int t = 0; t < 2; ++t) {
        const int g = tid * 2 + t;
        const float* bp = basis + g * 24;
        float acc = 0.f;
        #pragma unroll
        for (int s = 0; s < 24; ++s) acc += bp[s] * kparam[s * 8 + h];
        Wl[(g & 63) * 8 + (g >> 6)] = acc;
    }
    __syncthreads();
    const int f  = (blk & 15) * 32 + (tid >> 3);
    const int g1 = tid & 7;
    const int f1 = f >> 6, f2 = (f >> 3) & 7, f3 = f & 7;
    const int kb = (f1 * g1) & 7;
    float pr = 0.f, pi = 0.f;
    for (int g2 = 0; g2 < 8; ++g2) {
        const int k2 = kb + f2 * g2;
        const float* wrow = &Wl[g2 * 64 + g1];
        #pragma unroll
        for (int g3 = 0; g3 < 8; ++g3) {
            const int k = (k2 + f3 * g3) & 7;
            const float w = wrow[g3 * 8];
            pr += w * CT[k];
            pi += w * ST[k];
        }
    }
    pr += __shfl_xor(pr, 1); pi += __shfl_xor(pi, 1);
    pr += __shfl_xor(pr, 2); pi += __shfl_xor(pi, 2);
    pr += __shfl_xor(pr, 4); pi += __shfl_xor(pi, 4);
    if (g1 == 0)
        V[h * 512 + f] = make_float2(pr * (1.f / 512.f), pi * (1.f / 512.f));
}

// ---------------------------------------------------------------- main kernel
// 1024 WGs x 256 thr. WG = (b = bid>>5, c0 = (bid&31)*16) = 8 packed cubes.
// Wave w owns cubes 2w, 2w+1 exclusively -> wave-local fences between phases.
// Swizzled complex slot within cube: p1*64 + p2*8 + (p3^p2^p1).
__global__ __launch_bounds__(256, 5)
void eqfft_main(const float* __restrict__ x,
                const float2* __restrict__ V,
                float* __restrict__ out)
{
    __shared__ float2 lds[8 * 512];   // 32 KB exact -> 5 blocks/CU

    const int tid = threadIdx.x;
    const int bid = blockIdx.x;
    const int b   = bid >> 5;
    const int c0  = (bid & 31) * 16;

    const float* xb = x   + (size_t)b * 262144 + c0;
    float*       ob = out + (size_t)b * 262144 + c0;

    // ---- stage-in + pack: 64B-contiguous rows per WG ----
    #pragma unroll
    for (int t = 0; t < 4; ++t) {
        const int G = t * 256 + tid;
        const int p = G >> 1;
        const int u = G & 1;
        const float4 A  = *(const float4*)(xb + p * 512 + u * 4);
        const float4 Bv = *(const float4*)(xb + p * 512 + u * 4 + 8);
        const int p1 = p >> 6, p2 = (p >> 3) & 7, p3 = p & 7;
        const int s  = p1 * 64 + p2 * 8 + (p3 ^ p2 ^ p1);
        float2* dst = lds + (u * 4) * 512 + s;
        dst[0 * 512] = make_float2(A.x, Bv.x);
        dst[1 * 512] = make_float2(A.y, Bv.y);
        dst[2 * 512] = make_float2(A.z, Bv.z);
        dst[3 * 512] = make_float2(A.w, Bv.w);
    }
    __syncthreads();

    const int lane = tid & 63;
    const int wid  = tid >> 6;
    const int q0   = wid * 2;
    const int hi3  = lane >> 3, lo3 = lane & 7;
    const int xs   = lo3 ^ hi3;          // shared swizzle term, all phases

    float r0[8], i0[8], r1[8], i1[8];

    // ---- phase p3 fwd: lane=(p1,p2); slot = q*512 + p1*64+p2*8 + (xs^j) ----
    {
        float2* c0p = lds + q0 * 512 + hi3 * 64 + lo3 * 8;
        float2* c1p = c0p + 512;
        #pragma unroll
        for (int j = 0; j < 8; ++j) { const float2 z = c0p[xs ^ j]; r0[j] = z.x; i0[j] = z.y; }
        #pragma unroll
        for (int j = 0; j < 8; ++j) { const float2 z = c1p[xs ^ j]; r1[j] = z.x; i1[j] = z.y; }
        dft8<false>(r0, i0); dft8<false>(r1, i1);
        #pragma unroll
        for (int j = 0; j < 8; ++j) c0p[xs ^ j] = make_float2(r0[j], i0[j]);
        #pragma unroll
        for (int j = 0; j < 8; ++j) c1p[xs ^ j] = make_float2(r1[j], i1[j]);
    }
    wave_fence();

    // ---- phase p2 fwd: lane=(p1,p3); slot = q*512 + p1*64 + j*8 + (xs^j) ----
    {
        float2* c0p = lds + q0 * 512 + hi3 * 64;
        float2* c1p = c0p + 512;
        #pragma unroll
        for (int j = 0; j < 8; ++j) { const float2 z = c0p[j * 8 + (xs ^ j)]; r0[j] = z.x; i0[j] = z.y; }
        #pragma unroll
        for (int j = 0; j < 8; ++j) { const float2 z = c1p[j * 8 + (xs ^ j)]; r1[j] = z.x; i1[j] = z.y; }
        dft8<false>(r0, i0); dft8<false>(r1, i1);
        #pragma unroll
        for (int j = 0; j < 8; ++j) c0p[j * 8 + (xs ^ j)] = make_float2(r0[j], i0[j]);
        #pragma unroll
        for (int j = 0; j < 8; ++j) c1p[j * 8 + (xs ^ j)] = make_float2(r1[j], i1[j]);
    }
    wave_fence();

    // ---- phase p1 fwd + V + p1 inv (fused): lane=(p2,p3);
    //      slot = q*512 + p2*8 + j*64 + (xs^j); V idx = q*512 + lane + 64j ----
    {
        const float2* v0 = V + q0 * 512 + lane;
        const float2* v1 = v0 + 512;
        float2 va[8], vb[8];
        #pragma unroll
        for (int j = 0; j < 8; ++j) { va[j] = v0[j * 64]; vb[j] = v1[j * 64]; }

        float2* c0p = lds + q0 * 512 + hi3 * 8;
        float2* c1p = c0p + 512;
        #pragma unroll
        for (int j = 0; j < 8; ++j) { const float2 z = c0p[j * 64 + (xs ^ j)]; r0[j] = z.x; i0[j] = z.y; }
        #pragma unroll
        for (int j = 0; j < 8; ++j) { const float2 z = c1p[j * 64 + (xs ^ j)]; r1[j] = z.x; i1[j] = z.y; }
        dft8<false>(r0, i0); dft8<false>(r1, i1);
        #pragma unroll
        for (int j = 0; j < 8; ++j) {
            float nr = r0[j] * va[j].x - i0[j] * va[j].y;
            i0[j]    = r0[j] * va[j].y + i0[j] * va[j].x;
            r0[j]    = nr;
            nr       = r1[j] * vb[j].x - i1[j] * vb[j].y;
            i1[j]    = r1[j] * vb[j].y + i1[j] * vb[j].x;
            r1[j]    = nr;
        }
        dft8<true>(r0, i0); dft8<true>(r1, i1);
        #pragma unroll
        for (int j = 0; j < 8; ++j) c0p[j * 64 + (xs ^ j)] = make_float2(r0[j], i0[j]);
        #pragma unroll
        for (int j = 0; j < 8; ++j) c1p[j * 64 + (xs ^ j)] = make_float2(r1[j], i1[j]);
    }
    wave_fence();

    // ---- phase p2 inv ----
    {
        float2* c0p = lds + q0 * 512 + hi3 * 64;
        float2* c1p = c0p + 512;
        #pragma unroll
        for (int j = 0; j < 8; ++j) { const float2 z = c0p[j * 8 + (xs ^ j)]; r0[j] = z.x; i0[j] = z.y; }
        #pragma unroll
        for (int j = 0; j < 8; ++j) { const float2 z = c1p[j * 8 + (xs ^ j)]; r1[j] = z.x; i1[j] = z.y; }
        dft8<true>(r0, i0); dft8<true>(r1, i1);
        #pragma unroll
        for (int j = 0; j < 8; ++j) c0p[j * 8 + (xs ^ j)] = make_float2(r0[j], i0[j]);
        #pragma unroll
        for (int j = 0; j < 8; ++j) c1p[j * 8 + (xs ^ j)] = make_float2(r1[j], i1[j]);
    }
    wave_fence();

    // ---- phase p3 inv ----
    {
        float2* c0p = lds + q0 * 512 + hi3 * 64 + lo3 * 8;
        float2* c1p = c0p + 512;
        #pragma unroll
        for (int j = 0; j < 8; ++j) { const float2 z = c0p[xs ^ j]; r0[j] = z.x; i0[j] = z.y; }
        #pragma unroll
        for (int j = 0; j < 8; ++j) { const float2 z = c1p[xs ^ j]; r1[j] = z.x; i1[j] = z.y; }
        dft8<true>(r0, i0); dft8<true>(r1, i1);
        #pragma unroll
        for (int j = 0; j < 8; ++j) c0p[xs ^ j] = make_float2(r0[j], i0[j]);
        #pragma unroll
        for (int j = 0; j < 8; ++j) c1p[xs ^ j] = make_float2(r1[j], i1[j]);
    }
    __syncthreads();

    // ---- copy-out (unpack: re -> channel c, im -> channel c+8) ----
    #pragma unroll
    for (int t = 0; t < 4; ++t) {
        const int G = t * 256 + tid;
        const int p = G >> 1;
        const int u = G & 1;
        const int p1 = p >> 6, p2 = (p >> 3) & 7, p3 = p & 7;
        const int s  = p1 * 64 + p2 * 8 + (p3 ^ p2 ^ p1);
        const float2* src = lds + (u * 4) * 512 + s;
        const float2 z0 = src[0 * 512];
        const float2 z1 = src[1 * 512];
        const float2 z2 = src[2 * 512];
        const float2 z3 = src[3 * 512];
        *(float4*)(ob + p * 512 + u * 4)     = make_float4(z0.x, z1.x, z2.x, z3.x);
        *(float4*)(ob + p * 512 + u * 4 + 8) = make_float4(z0.y, z1.y, z2.y, z3.y);
    }
}

extern "C" void kernel_launch(void* const* d_in, const int* in_sizes, int n_in,
                              void* d_out, int out_size, void* d_ws, size_t ws_size,
                              hipStream_t stream)
{
    const float* x      = (const float*)d_in[0];   // [32][512][512]
    const float* basis  = (const float*)d_in[1];   // [512][24]
    const float* kparam = (const float*)d_in[2];   // [24][8]
    float* out          = (float*)d_out;
    float2* V           = (float2*)d_ws;           // 8*512*8B = 32 KB scratch

    hipLaunchKernelGGL(eqfft_prep, dim3(128),  dim3(256), 0, stream, basis, kparam, V);
    hipLaunchKernelGGL(eqfft_main, dim3(1024), dim3(256), 0, stream, x, V, out);
}

// Round 9
// 102.176 us; speedup vs baseline: 1.1052x; 1.0426x over previous
//
#include <hip/hip_runtime.h>

// EquivariantLinear = per-head circular correlation on Z_8^3 via 8x8x8 FFT:
//   out = IDFT( DFT(x) * V ),  V[h][f] = conj(DFT(W_h))[f] / 512.
// Round-9: max-TLP structure. R8 lesson: wave-fence (lgkmcnt0+sched_barrier)
// and runtime-XOR LDS addressing both regress -> back to __syncthreads +
// immediate-offset padded strides. Plateau cause = latency at 16 waves/CU in
// lockstep; fix: half tiles (8ch = 4 packed cubes, 16.9KB LDS, 1 pencil per
// thread) -> 2048 blocks x 256thr = 8 blocks/CU = 32 waves/CU (8/SIMD max),
// organically desynced. Strides S2=16/S1=132/CST=1056 give 16B-aligned b128
// on p3 phases + corner turns; verified exact-minimum bank usage per access.
// Complex-pack retained: cube q = channels (c0+q, c0+q+8), head = (c0&7)+q.

#define S2C  0.70710678118654752f
#define LS2  16      // p2 stride (words) — b128-aligned
#define LS1  132     // p1 stride = 8*16 + 4 pad (528 B, 16B-aligned)
#define LCST 1056    // cube stride = 8*132 (4224 B); 4 cubes = 16.9 KB

// ---------------------------------------------------------------- DFT-8 in-place
template <bool INV>
__device__ __forceinline__ void dft8(float* R, float* I)
{
    float t0r = R[0] + R[4], t0i = I[0] + I[4];
    float t1r = R[1] + R[5], t1i = I[1] + I[5];
    float t2r = R[2] + R[6], t2i = I[2] + I[6];
    float t3r = R[3] + R[7], t3i = I[3] + I[7];
    float b0r = R[0] - R[4], b0i = I[0] - I[4];
    float d1r = R[1] - R[5], d1i = I[1] - I[5];
    float d2r = R[2] - R[6], d2i = I[2] - I[6];
    float d3r = R[3] - R[7], d3i = I[3] - I[7];
    float b1r, b1i, b2r, b2i, b3r, b3i;
    if (!INV) {
        b1r = (d1r + d1i) * S2C;  b1i = (d1i - d1r) * S2C;
        b2r = d2i;                b2i = -d2r;
        b3r = (d3i - d3r) * S2C;  b3i = -(d3r + d3i) * S2C;
    } else {
        b1r = (d1r - d1i) * S2C;  b1i = (d1i + d1r) * S2C;
        b2r = -d2i;               b2i = d2r;
        b3r = -(d3r + d3i) * S2C; b3i = (d3r - d3i) * S2C;
    }
    float u0r = t0r + t2r, u0i = t0i + t2i;
    float u1r = t1r + t3r, u1i = t1i + t3i;
    float u2r = t0r - t2r, u2i = t0i - t2i;
    float e3r = t1r - t3r, e3i = t1i - t3i;
    float u3r, u3i;
    if (!INV) { u3r = e3i;  u3i = -e3r; }
    else      { u3r = -e3i; u3i = e3r;  }
    R[0] = u0r + u1r; I[0] = u0i + u1i;
    R[4] = u0r - u1r; I[4] = u0i - u1i;
    R[2] = u2r + u3r; I[2] = u2i + u3i;
    R[6] = u2r - u3r; I[6] = u2i - u3i;
    float v0r = b0r + b2r, v0i = b0i + b2i;
    float v1r = b1r + b3r, v1i = b1i + b3i;
    float v2r = b0r - b2r, v2i = b0i - b2i;
    float w3r = b1r - b3r, w3i = b1i - b3i;
    float v3r, v3i;
    if (!INV) { v3r = w3i;  v3i = -w3r; }
    else      { v3r = -w3i; v3i = w3r;  }
    R[1] = v0r + v1r; I[1] = v0i + v1i;
    R[5] = v0r - v1r; I[5] = v0i - v1i;
    R[3] = v2r + v3r; I[3] = v2i + v3i;
    R[7] = v2r - v3r; I[7] = v2i - v3i;
}

// ---------------------------------------------------------------- prep kernel
__device__ const float CTAB8[8] = {1.f, S2C, 0.f, -S2C, -1.f, -S2C, 0.f, S2C};
__device__ const float STAB8[8] = {0.f, S2C, 1.f, S2C, 0.f, -S2C, -1.f, -S2C};

__global__ __launch_bounds__(256)
void eqfft_prep(const float* __restrict__ basis,
                const float* __restrict__ kparam,
                float2* __restrict__ V)
{
    __shared__ float Wl[512];
    __shared__ float CT[8], ST[8];
    const int tid = threadIdx.x;
    const int blk = blockIdx.x;    // 128 blocks: h = blk>>4, f-base = (blk&15)*32
    const int h   = blk >> 4;
    if (tid < 8) { CT[tid] = CTAB8[tid]; ST[tid] = STAB8[tid]; }
    #pragma unroll
    for (int t = 0; t < 2; ++t) {
        const int g = tid * 2 + t;
        const float* bp = basis + g * 24;
        float acc = 0.f;
        #pragma unroll
        for (int s = 0; s < 24; ++s) acc += bp[s] * kparam[s * 8 + h];
        Wl[(g & 63) * 8 + (g >> 6)] = acc;
    }
    __syncthreads();
    const int f  = (blk & 15) * 32 + (tid >> 3);
    const int g1 = tid & 7;
    const int f1 = f >> 6, f2 = (f >> 3) & 7, f3 = f & 7;
    const int kb = (f1 * g1) & 7;
    float pr = 0.f, pi = 0.f;
    for (int g2 = 0; g2 < 8; ++g2) {
        const int k2 = kb + f2 * g2;
        const float* wrow = &Wl[g2 * 64 + g1];
        #pragma unroll
        for (int g3 = 0; g3 < 8; ++g3) {
            const int k = (k2 + f3 * g3) & 7;
            const float w = wrow[g3 * 8];
            pr += w * CT[k];
            pi += w * ST[k];
        }
    }
    pr += __shfl_xor(pr, 1); pi += __shfl_xor(pi, 1);
    pr += __shfl_xor(pr, 2); pi += __shfl_xor(pi, 2);
    pr += __shfl_xor(pr, 4); pi += __shfl_xor(pi, 4);
    if (g1 == 0)
        V[h * 512 + f] = make_float2(pr * (1.f / 512.f), pi * (1.f / 512.f));
}

// ---------------------------------------------------------------- main kernel
// 2048 blocks x 256 thr. Tile T: b = T>>6, r = T&63, c0 = (r>>1)*16+(r&1)*4;
// channels {c0..c0+3} packed with {c0+8..c0+11} -> 4 cubes, head (c0&7)+q.
// Wave w owns cube w; thread = 1 pencil per phase.
__global__ __launch_bounds__(256, 6)
void eqfft_main(const float* __restrict__ x,
                const float2* __restrict__ V,
                float* __restrict__ out)
{
    __shared__ __align__(16) float lds[4 * LCST];   // 16.9 KB -> 8 blocks/CU

    const int tid = threadIdx.x;
    const int d   = blockIdx.x;
    // pair co-XCD swizzle: work tiles (2k,2k+1) share 64B x-rows; map them to
    // dispatch ids d and d+8 (same XCD under round-robin). Bijective (2048%16==0).
    const int T   = (d & 7) * 2 + ((d >> 3) & 1) + (d >> 4) * 16;
    const int b   = T >> 6;
    const int r   = T & 63;
    const int c0  = (r >> 1) * 16 + (r & 1) * 4;

    const float* xb = x   + (size_t)b * 262144 + c0;
    float*       ob = out + (size_t)b * 262144 + c0;

    // ---- stage-in + complex-pack: thread handles 2 whole rows ----
    #pragma unroll
    for (int i = 0; i < 2; ++i) {
        const int p = i * 256 + tid;
        const float4 A  = *(const float4*)(xb + p * 512);       // ch c0..c0+3
        const float4 Bv = *(const float4*)(xb + p * 512 + 8);   // ch c0+8..c0+11
        float* dst = lds + (p >> 6) * LS1 + ((p >> 3) & 7) * LS2 + (p & 7) * 2;
        *(float2*)(dst + 0 * LCST) = make_float2(A.x, Bv.x);
        *(float2*)(dst + 1 * LCST) = make_float2(A.y, Bv.y);
        *(float2*)(dst + 2 * LCST) = make_float2(A.z, Bv.z);
        *(float2*)(dst + 3 * LCST) = make_float2(A.w, Bv.w);
    }
    __syncthreads();

    const int q    = tid >> 6;          // cube = wave id
    const int lane = tid & 63;
    const int hi   = lane >> 3, lo = lane & 7;
    float* const cb = lds + q * LCST;
    float R[8], I[8];

    // ---- p3 fwd: lane=(p1,p2); contiguous complex -> 4x b128 each way ----
    {
        float* pp = cb + hi * LS1 + lo * LS2;
        #pragma unroll
        for (int k = 0; k < 4; ++k) {
            const float4 z = *(const float4*)(pp + 4 * k);
            R[2*k] = z.x; I[2*k] = z.y; R[2*k+1] = z.z; I[2*k+1] = z.w;
        }
        dft8<false>(R, I);
        #pragma unroll
        for (int k = 0; k < 4; ++k)
            *(float4*)(pp + 4 * k) = make_float4(R[2*k], I[2*k], R[2*k+1], I[2*k+1]);
    }
    __syncthreads();

    // ---- p2 fwd: lane=(p1,p3); stride LS2, immediate offsets ----
    {
        float* pp = cb + hi * LS1 + lo * 2;
        #pragma unroll
        for (int j = 0; j < 8; ++j) { const float2 z = *(const float2*)(pp + j * LS2); R[j] = z.x; I[j] = z.y; }
        dft8<false>(R, I);
        #pragma unroll
        for (int j = 0; j < 8; ++j) *(float2*)(pp + j * LS2) = make_float2(R[j], I[j]);
    }
    __syncthreads();

    // ---- p1 fwd + V + p1 inv (fused): lane=(p2,p3); stride LS1 ----
    {
        const int h = ((r & 1) << 2) + q;
        const float2* vp = V + h * 512 + lane;     // f2*8+f3 == lane
        float2 va[8];
        #pragma unroll
        for (int j = 0; j < 8; ++j) va[j] = vp[j * 64];

        float* pp = cb + hi * LS2 + lo * 2;
        #pragma unroll
        for (int j = 0; j < 8; ++j) { const float2 z = *(const float2*)(pp + j * LS1); R[j] = z.x; I[j] = z.y; }
        dft8<false>(R, I);
        #pragma unroll
        for (int j = 0; j < 8; ++j) {
            const float nr = R[j] * va[j].x - I[j] * va[j].y;
            I[j] = R[j] * va[j].y + I[j] * va[j].x;
            R[j] = nr;
        }
        dft8<true>(R, I);
        #pragma unroll
        for (int j = 0; j < 8; ++j) *(float2*)(pp + j * LS1) = make_float2(R[j], I[j]);
    }
    __syncthreads();

    // ---- p2 inv ----
    {
        float* pp = cb + hi * LS1 + lo * 2;
        #pragma unroll
        for (int j = 0; j < 8; ++j) { const float2 z = *(const float2*)(pp + j * LS2); R[j] = z.x; I[j] = z.y; }
        dft8<true>(R, I);
        #pragma unroll
        for (int j = 0; j < 8; ++j) *(float2*)(pp + j * LS2) = make_float2(R[j], I[j]);
    }
    __syncthreads();

    // ---- p3 inv (keep full complex: re = ch c, im = ch c+8) ----
    {
        float* pp = cb + hi * LS1 + lo * LS2;
        #pragma unroll
        for (int k = 0; k < 4; ++k) {
            const float4 z = *(const float4*)(pp + 4 * k);
            R[2*k] = z.x; I[2*k] = z.y; R[2*k+1] = z.z; I[2*k+1] = z.w;
        }
        dft8<true>(R, I);
        #pragma unroll
        for (int k = 0; k < 4; ++k)
            *(float4*)(pp + 4 * k) = make_float4(R[2*k], I[2*k], R[2*k+1], I[2*k+1]);
    }
    __syncthreads();

    // ---- copy-out (unpack) ----
    #pragma unroll
    for (int i = 0; i < 2; ++i) {
        const int p = i * 256 + tid;
        const float* src = lds + (p >> 6) * LS1 + ((p >> 3) & 7) * LS2 + (p & 7) * 2;
        const float2 z0 = *(const float2*)(src + 0 * LCST);
        const float2 z1 = *(const float2*)(src + 1 * LCST);
        const float2 z2 = *(const float2*)(src + 2 * LCST);
        const float2 z3 = *(const float2*)(src + 3 * LCST);
        *(float4*)(ob + p * 512)     = make_float4(z0.x, z1.x, z2.x, z3.x);
        *(float4*)(ob + p * 512 + 8) = make_float4(z0.y, z1.y, z2.y, z3.y);
    }
}

extern "C" void kernel_launch(void* const* d_in, const int* in_sizes, int n_in,
                              void* d_out, int out_size, void* d_ws, size_t ws_size,
                              hipStream_t stream)
{
    const float* x      = (const float*)d_in[0];   // [32][512][512]
    const float* basis  = (const float*)d_in[1];   // [512][24]
    const float* kparam = (const float*)d_in[2];   // [24][8]
    float* out          = (float*)d_out;
    float2* V           = (float2*)d_ws;           // 8*512*8B = 32 KB scratch

    hipLaunchKernelGGL(eqfft_prep, dim3(128),  dim3(256), 0, stream, basis, kparam, V);
    hipLaunchKernelGGL(eqfft_main, dim3(2048), dim3(256), 0, stream, x, V, out);
}